// Round 11
// baseline (211.642 us; speedup 1.0000x reference)
//
#include <hip/hip_runtime.h>
#include <hip/hip_bf16.h>
#include <hip/hip_cooperative_groups.h>
#include <math.h>

#define B_ 2
#define N_ 20000
#define C_ 64
#define K_ 16
#define CS_ 16
#define EPS_ 1e-5f

typedef float f32x4_t  __attribute__((ext_vector_type(4)));
typedef short bf16x8_t __attribute__((ext_vector_type(8)));
typedef short bf16x4_t __attribute__((ext_vector_type(4)));

__device__ __forceinline__ unsigned int packbf2(float a, float b)
{
    union { __hip_bfloat162 h; unsigned int u; } cv;
    cv.h = __float22bfloat162_rn(float2{a, b});
    return cv.u;
}
__device__ __forceinline__ float bf_lo(unsigned int w)
{
    return __builtin_bit_cast(float, w << 16);
}
__device__ __forceinline__ float bf_hi(unsigned int w)
{
    return __builtin_bit_cast(float, w & 0xFFFF0000u);
}
__device__ __forceinline__ void wave_fence()
{
    __builtin_amdgcn_wave_barrier();
}

#define WROW 72          // ushorts per w-tile row (144B)
#define WPN  (K_ * WROW) // 1152 per point
#define SS4  20          // sfb row stride (f32)
#define SPN  (K_ * SS4)  // 320 per point

// ---------------------------------------------------------------------------
// Fused cooperative kernel. 512 thr = 8 waves/block, grid = 4 blocks/CU x 256.
// Shared memory (39936B, 4/CU = 159744 <= 160K):
//   phase P: wtab[1536 uint4] | qp[2][832]u32 | kp[2][832]u32 | ctab[64]f4 | ptab[64]f4
//   phase A (aliases): wlds[8*1152]u16 | sfb[8*320]f32 | otile[64*9]f32
// Phase S: per-block table build (3 entries/thread).
// Phase P: grid-stride proj tile-pairs (waves 0-3 tile 2i, waves 4-7 tile 2i+1).
// threadfence + grid.sync (agent release: kv_t/xq2 visible cross-XCD).
// Phase A: per-block attn constants, grid-stride 8-point attn tiles.
// ---------------------------------------------------------------------------
__global__ __launch_bounds__(512, 8) void fused_kernel(
    const float* __restrict__ q, const float* __restrict__ kin,
    const float* __restrict__ coord, const int* __restrict__ nbr,
    const float* __restrict__ wq, const float* __restrict__ wk,
    const float* __restrict__ wv,
    const float* __restrict__ bq, const float* __restrict__ bk,
    const float* __restrict__ bv,
    const float* __restrict__ p1_w, const float* __restrict__ p1_b,
    const float* __restrict__ p_bn_g, const float* __restrict__ p_bn_b,
    const float* __restrict__ p_bn_m, const float* __restrict__ p_bn_v,
    const float* __restrict__ p2_w, const float* __restrict__ p2_b,
    const float* __restrict__ w_bn1_g, const float* __restrict__ w_bn1_b,
    const float* __restrict__ w_bn1_m, const float* __restrict__ w_bn1_v,
    const float* __restrict__ w1_w, const float* __restrict__ w1_b,
    const float* __restrict__ w_bn2_g, const float* __restrict__ w_bn2_b,
    const float* __restrict__ w_bn2_m, const float* __restrict__ w_bn2_v,
    const float* __restrict__ w2_w, const float* __restrict__ w2_b,
    unsigned int* __restrict__ xq2, unsigned int* __restrict__ kv_t,
    float* __restrict__ out, int nblk)
{
    __shared__ __align__(16) char smem[39936];
    uint4*        wtab = reinterpret_cast<uint4*>(smem);                 // 24576B
    unsigned int* qpb  = reinterpret_cast<unsigned int*>(smem + 24576);  // 6656B
    unsigned int* kpb  = reinterpret_cast<unsigned int*>(smem + 31232);  // 6656B
    float4*       ctab = reinterpret_cast<float4*>(smem + 37888);        // 1024B
    float4*       ptab = reinterpret_cast<float4*>(smem + 38912);        // 1024B

    const int t   = threadIdx.x;
    const int wid = __builtin_amdgcn_readfirstlane(t >> 6);   // 0..7
    const int l   = t & 63;
    const int col = l & 15;
    const int qd  = l >> 4;
    const int og  = wid & 3;
    const int h2  = wid >> 2;

    union bf8u { bf16x8_t v; uint4 u4; unsigned int u[4]; };
    union bf4u { bf16x4_t v; uint2 u2; };

    // ==== phase S: per-block tables ====
    for (int e = t; e < 1536; e += 512) {
        int m = e >> 9, rem = e & 511;
        int eog = rem >> 7, half = (rem >> 6) & 1, el = rem & 63;
        const float* W = (m == 0) ? wq : ((m == 1) ? wk : wv);
        const float* base = W + (size_t)(eog * 16 + (el & 15)) * C_ + half * 32 + (el >> 4) * 8;
        uint4 o;
        o.x = packbf2(base[0], base[1]); o.y = packbf2(base[2], base[3]);
        o.z = packbf2(base[4], base[5]); o.w = packbf2(base[6], base[7]);
        wtab[e] = o;
    }
    if (t < 64) {
        float s   = w_bn1_g[t] * rsqrtf(w_bn1_v[t] + EPS_);
        float b1f = w_bn1_b[t] - w_bn1_m[t] * s;
        ctab[t] = float4{s, s * bq[t] - b1f, bk[t], bv[t]};
    } else if (t < 128) {
        int u = t - 64;
        ptab[u] = float4{p2_w[u*3+0], p2_w[u*3+1], p2_w[u*3+2], p2_b[u]};
    }

    // pos-MLP layer-1 constants (wave-uniform s_loads), hoisted
    float pbs[3], pbb[3];
#pragma unroll
    for (int j = 0; j < 3; j++) {
        float s = p_bn_g[j] * rsqrtf(p_bn_v[j] + EPS_);
        pbs[j] = s;
        pbb[j] = (p1_b[j] - p_bn_m[j]) * s + p_bn_b[j];
    }
    float p1w[9];
#pragma unroll
    for (int j = 0; j < 9; j++) p1w[j] = p1_w[j];

    __syncthreads();

    // ==== phase P: proj, grid-stride tile pairs ====
    unsigned int* qp = qpb + h2 * 832;
    unsigned int* kp = kpb + h2 * 832;
    for (int i = blockIdx.x; i < 1250; i += nblk) {
        const int tp  = i * 2 + h2;
        const int pt0 = tp * 16;
        const int pt  = pt0 + col;
        const int b   = pt0 / N_;          // 20000%16==0: no straddle
        const int n   = pt - b * N_;
        const size_t cb = (size_t)b * C_ * N_ + n;

        // cooperative input staging (each element once per 4-wave group)
#pragma unroll
        for (int r = 0; r < 2; r++) {
            int cp = (og << 3) + (qd << 1) + r;
            int ci = cp * 2;
            float q0 = q[cb + (size_t)ci * N_];
            float q1 = q[cb + (size_t)(ci + 1) * N_];
            float k0 = kin[cb + (size_t)ci * N_];
            float k1 = kin[cb + (size_t)(ci + 1) * N_];
            qp[cp * 26 + col] = packbf2(q0, q1);
            kp[cp * 26 + col] = packbf2(k0, k1);
        }
        __syncthreads();

        bf8u awq[2], awk[2], awv[2], bq_[2], bk_[2];
#pragma unroll
        for (int half = 0; half < 2; half++) {
            awq[half].u4 = wtab[0 * 512 + og * 128 + half * 64 + l];
            awk[half].u4 = wtab[1 * 512 + og * 128 + half * 64 + l];
            awv[half].u4 = wtab[2 * 512 + og * 128 + half * 64 + l];
#pragma unroll
            for (int i2 = 0; i2 < 4; i2++) {
                int cp = half * 16 + qd * 4 + i2;
                bq_[half].u[i2] = qp[cp * 26 + col];
                bk_[half].u[i2] = kp[cp * 26 + col];
            }
        }

        f32x4_t uq = {0.f, 0.f, 0.f, 0.f};
        f32x4_t uv = {0.f, 0.f, 0.f, 0.f};
        f32x4_t uk = {0.f, 0.f, 0.f, 0.f};
        uq = __builtin_amdgcn_mfma_f32_16x16x32_bf16(awq[0].v, bq_[0].v, uq, 0, 0, 0);
        uq = __builtin_amdgcn_mfma_f32_16x16x32_bf16(awq[1].v, bq_[1].v, uq, 0, 0, 0);
        uv = __builtin_amdgcn_mfma_f32_16x16x32_bf16(awv[0].v, bq_[0].v, uv, 0, 0, 0);
        uv = __builtin_amdgcn_mfma_f32_16x16x32_bf16(awv[1].v, bq_[1].v, uv, 0, 0, 0);
        uk = __builtin_amdgcn_mfma_f32_16x16x32_bf16(awk[0].v, bk_[0].v, uk, 0, 0, 0);
        uk = __builtin_amdgcn_mfma_f32_16x16x32_bf16(awk[1].v, bk_[1].v, uk, 0, 0, 0);

        float cx = coord[pt * 3 + 0], cy = coord[pt * 3 + 1], cz = coord[pt * 3 + 2];
        float h0 = fmaxf(0.f, (p1w[0]*cx + p1w[1]*cy + p1w[2]*cz) * pbs[0] + pbb[0]);
        float h1 = fmaxf(0.f, (p1w[3]*cx + p1w[4]*cy + p1w[5]*cz) * pbs[1] + pbb[1]);
        float h2f = fmaxf(0.f, (p1w[6]*cx + p1w[7]*cy + p1w[8]*cz) * pbs[2] + pbb[2]);

        const int ch0 = og * 16 + qd * 4;
        float xv2[4];
        uint4 kvo;
#pragma unroll
        for (int rr = 0; rr < 4; rr++) {
            const float4 ct  = ctab[ch0 + rr];
            const float4 pt4 = ptab[ch0 + rr];
            float pos = fmaf(pt4.x, h0, fmaf(pt4.y, h1, fmaf(pt4.z, h2f, pt4.w)));
            xv2[rr]   = fmaf(ct.x, uq[rr], ct.y);
            float kk  = ct.x * (uk[rr] + ct.z + pos);
            float vv  = uv[rr] + ct.w + pos;
            (&kvo.x)[rr] = packbf2(kk, vv);
        }
        uint2 xqo;
        xqo.x = packbf2(xv2[0], xv2[1]);
        xqo.y = packbf2(xv2[2], xv2[3]);
        *reinterpret_cast<uint2*>(xq2 + (size_t)pt * 32 + (ch0 >> 1)) = xqo;
        *reinterpret_cast<uint4*>(kv_t + (size_t)pt * C_ + ch0) = kvo;

        __syncthreads();   // all qp/kp reads done before next-iter overwrite
    }

    // ==== visibility across XCDs, then grid barrier ====
    __threadfence();
    cooperative_groups::this_grid().sync();

    // ==== phase A: attention ====
    unsigned short* wlds = reinterpret_cast<unsigned short*>(smem) + wid * WPN;
    float* sfb   = reinterpret_cast<float*>(smem + 18432) + wid * SPN;
    float* otile = reinterpret_cast<float*>(smem + 28672);

    const int al    = l & 15;
    const int cpair = l & 31;
    const int kh    = l >> 5;
    const int c0    = cpair * 2;

    // per-block attn constants (amortized over ~5000/nblk tiles)
    bf8u a1q0, a1q1; bf4u a2q;
    {
        const float* base = w1_w + (size_t)al * C_ + qd * 8;
        float4 f0 = *reinterpret_cast<const float4*>(base);
        float4 f1 = *reinterpret_cast<const float4*>(base + 4);
        a1q0.u4 = uint4{packbf2(f0.x, f0.y), packbf2(f0.z, f0.w),
                        packbf2(f1.x, f1.y), packbf2(f1.z, f1.w)};
        f0 = *reinterpret_cast<const float4*>(base + 32);
        f1 = *reinterpret_cast<const float4*>(base + 36);
        a1q1.u4 = uint4{packbf2(f0.x, f0.y), packbf2(f0.z, f0.w),
                        packbf2(f1.x, f1.y), packbf2(f1.z, f1.w)};
        float4 f2 = *reinterpret_cast<const float4*>(w2_w + al * 16 + qd * 4);
        a2q.u2 = uint2{packbf2(f2.x, f2.y), packbf2(f2.z, f2.w)};
    }
    float4 zsc4, zbi4, tbi4;
    {
        const float4 g2  = *reinterpret_cast<const float4*>(w_bn2_g + 4 * qd);
        const float4 bb2 = *reinterpret_cast<const float4*>(w_bn2_b + 4 * qd);
        const float4 m2  = *reinterpret_cast<const float4*>(w_bn2_m + 4 * qd);
        const float4 v2  = *reinterpret_cast<const float4*>(w_bn2_v + 4 * qd);
        const float4 ub  = *reinterpret_cast<const float4*>(w1_b + 4 * qd);
        const float4 tb  = *reinterpret_cast<const float4*>(w2_b + 4 * qd);
#pragma unroll
        for (int rr = 0; rr < 4; rr++) {
            float s = (&g2.x)[rr] * rsqrtf((&v2.x)[rr] + EPS_);
            (&zsc4.x)[rr] = s;
            (&zbi4.x)[rr] = ((&ub.x)[rr] - (&m2.x)[rr]) * s + (&bb2.x)[rr];
            (&tbi4.x)[rr] = (&tb.x)[rr];
        }
    }

    for (int ta = blockIdx.x; ta < 5000; ta += nblk) {
        const int pt0 = ta * 8;            // 20000%8==0: no straddle
        const int b   = pt0 / N_;
        const int bB  = b * N_;
        const int bn  = pt0 + wid;

        // gather 8 neighbor rows x 2 channels
        const int* nb = nbr + (size_t)bn * K_;
        uint2 kvw[8];
#pragma unroll
        for (int j = 0; j < 8; j++) {
            int ia = nb[j];                // wave-uniform -> s_load
            int ib = nb[8 + j];
            int idx = (kh != 0) ? ib : ia;
            kvw[j] = *reinterpret_cast<const uint2*>(kv_t + ((size_t)(bB + idx) * C_ + c0));
        }
        const unsigned int xqu = xq2[(size_t)bn * 32 + cpair];
        const float xq0 = bf_lo(xqu);
        const float xq1 = bf_hi(xqu);

#pragma unroll
        for (int j = 0; j < 8; j++) {
            float w0 = fmaxf(0.f, bf_lo(kvw[j].x) - xq0);
            float w1 = fmaxf(0.f, bf_lo(kvw[j].y) - xq1);
            *reinterpret_cast<unsigned int*>(wlds + (kh * 8 + j) * WROW + c0) = packbf2(w0, w1);
        }
        wave_fence();

        // u = w1 @ w^T
        const bf16x8_t b0 = *reinterpret_cast<const bf16x8_t*>(wlds + al * WROW + qd * 8);
        const bf16x8_t b1 = *reinterpret_cast<const bf16x8_t*>(wlds + al * WROW + 32 + qd * 8);
        f32x4_t u = {0.f, 0.f, 0.f, 0.f};
        u = __builtin_amdgcn_mfma_f32_16x16x32_bf16(a1q0.v, b0, u, 0, 0, 0);
        u = __builtin_amdgcn_mfma_f32_16x16x32_bf16(a1q1.v, b1, u, 0, 0, 0);

        union { bf16x4_t v; unsigned int u2[2]; } zb;
        {
            float z0 = fmaxf(0.f, u[0] * zsc4.x + zbi4.x);
            float z1 = fmaxf(0.f, u[1] * zsc4.y + zbi4.y);
            float z2 = fmaxf(0.f, u[2] * zsc4.z + zbi4.z);
            float z3 = fmaxf(0.f, u[3] * zsc4.w + zbi4.w);
            zb.u2[0] = packbf2(z0, z1);
            zb.u2[1] = packbf2(z2, z3);
        }

        // t = w2 @ z
        f32x4_t t4 = {0.f, 0.f, 0.f, 0.f};
        t4 = __builtin_amdgcn_mfma_f32_16x16x16bf16_1k(a2q.v, zb.v, t4, 0, 0, 0);

        // softmax over neighbors, rows g = 4qd+rr, col k = al
        float4 sv;
#pragma unroll
        for (int rr = 0; rr < 4; rr++) {
            float e = __expf(t4[rr] + (&tbi4.x)[rr]);   // |t| << 80
            float s = e;
            s += __shfl_xor(s, 1);
            s += __shfl_xor(s, 2);
            s += __shfl_xor(s, 4);
            s += __shfl_xor(s, 8);
            (&sv.x)[rr] = e * __builtin_amdgcn_rcpf(s);
        }
        *reinterpret_cast<float4*>(sfb + al * SS4 + qd * 4) = sv;
        wave_fence();

        // out[c] = sum_k v[k][c] * soft[k][c&15]
        const int g0 = c0 & 15;
        float acc0 = 0.f, acc1 = 0.f;
#pragma unroll
        for (int j = 0; j < 8; j++) {
            float2 sp = *reinterpret_cast<const float2*>(sfb + (kh * 8 + j) * SS4 + g0);
            acc0 = fmaf(bf_hi(kvw[j].x), sp.x, acc0);
            acc1 = fmaf(bf_hi(kvw[j].y), sp.y, acc1);
        }
        acc0 += __shfl_xor(acc0, 32);
        acc1 += __shfl_xor(acc1, 32);
        if (kh == 0) {
            otile[c0 * 9 + wid]       = acc0;
            otile[(c0 + 1) * 9 + wid] = acc1;
        }
        __syncthreads();

        {   // coalesced [B,C,N] write
            int c  = t >> 3;
            int nn = t & 7;
            out[(size_t)b * C_ * N_ + (size_t)c * N_ + (pt0 - bB) + nn] = otile[c * 9 + nn];
        }
        __syncthreads();   // otile reads done before next-iter overwrite
    }
}

// ---------------------------------------------------------------------------
extern "C" void kernel_launch(void* const* d_in, const int* in_sizes, int n_in,
                              void* d_out, int out_size, void* d_ws, size_t ws_size,
                              hipStream_t stream)
{
    const float* coord = (const float*)d_in[0];
    const float* q     = (const float*)d_in[1];
    const float* k     = (const float*)d_in[2];
    const int*   nbr   = (const int*)d_in[3];
    const float* wq = (const float*)d_in[4];
    const float* bq = (const float*)d_in[5];
    const float* wk = (const float*)d_in[6];
    const float* bk = (const float*)d_in[7];
    const float* wv = (const float*)d_in[8];
    const float* bv = (const float*)d_in[9];
    const float* p1_w = (const float*)d_in[10];
    const float* p1_b = (const float*)d_in[11];
    const float* p_bn_g = (const float*)d_in[12];
    const float* p_bn_b = (const float*)d_in[13];
    const float* p_bn_m = (const float*)d_in[14];
    const float* p_bn_v = (const float*)d_in[15];
    const float* p2_w = (const float*)d_in[16];
    const float* p2_b = (const float*)d_in[17];
    const float* w_bn1_g = (const float*)d_in[18];
    const float* w_bn1_b = (const float*)d_in[19];
    const float* w_bn1_m = (const float*)d_in[20];
    const float* w_bn1_v = (const float*)d_in[21];
    const float* w1_w = (const float*)d_in[22];
    const float* w1_b = (const float*)d_in[23];
    const float* w_bn2_g = (const float*)d_in[24];
    const float* w_bn2_b = (const float*)d_in[25];
    const float* w_bn2_m = (const float*)d_in[26];
    const float* w_bn2_v = (const float*)d_in[27];
    const float* w2_w = (const float*)d_in[28];
    const float* w2_b = (const float*)d_in[29];

    const size_t PTS = (size_t)B_ * N_;        // 40000
    char* wsb = (char*)d_ws;
    unsigned int* kv_t = (unsigned int*)wsb;                  // [PTS][64] u32
    unsigned int* xq2  = (unsigned int*)(wsb + PTS * C_ * 4); // [PTS][32] u32
    float* out = (float*)d_out;

    int occ = 0;
    hipOccupancyMaxActiveBlocksPerMultiprocessor(&occ, (const void*)fused_kernel, 512, 0);
    if (occ < 1) occ = 1;
    int nblk = occ * 256;
    if (nblk > 5000) nblk = 5000;

    void* args[] = {
        (void*)&q, (void*)&k, (void*)&coord, (void*)&nbr,
        (void*)&wq, (void*)&wk, (void*)&wv,
        (void*)&bq, (void*)&bk, (void*)&bv,
        (void*)&p1_w, (void*)&p1_b,
        (void*)&p_bn_g, (void*)&p_bn_b, (void*)&p_bn_m, (void*)&p_bn_v,
        (void*)&p2_w, (void*)&p2_b,
        (void*)&w_bn1_g, (void*)&w_bn1_b, (void*)&w_bn1_m, (void*)&w_bn1_v,
        (void*)&w1_w, (void*)&w1_b,
        (void*)&w_bn2_g, (void*)&w_bn2_b, (void*)&w_bn2_m, (void*)&w_bn2_v,
        (void*)&w2_w, (void*)&w2_b,
        (void*)&xq2, (void*)&kv_t, (void*)&out, (void*)&nblk
    };
    hipLaunchCooperativeKernel((const void*)fused_kernel, dim3(nblk), dim3(512),
                               args, 0, stream);
}

// Round 12
// 77.696 us; speedup vs baseline: 2.7240x; 2.7240x over previous
//
#include <hip/hip_runtime.h>
#include <hip/hip_bf16.h>
#include <math.h>

#define B_ 2
#define N_ 20000
#define C_ 64
#define K_ 16
#define CS_ 16
#define EPS_ 1e-5f

typedef float f32x4_t  __attribute__((ext_vector_type(4)));
typedef short bf16x8_t __attribute__((ext_vector_type(8)));
typedef short bf16x4_t __attribute__((ext_vector_type(4)));

__device__ __forceinline__ unsigned int packbf2(float a, float b)
{
    union { __hip_bfloat162 h; unsigned int u; } cv;
    cv.h = __float22bfloat162_rn(float2{a, b});
    return cv.u;
}
__device__ __forceinline__ float bf_lo(unsigned int w)
{
    return __builtin_bit_cast(float, w << 16);
}
__device__ __forceinline__ float bf_hi(unsigned int w)
{
    return __builtin_bit_cast(float, w & 0xFFFF0000u);
}
__device__ __forceinline__ void wave_fence()
{
    __builtin_amdgcn_wave_barrier();
}

// ---------------------------------------------------------------------------
// Kernel 0: setup, 6 blocks, disjoint work (R10, unchanged).
// ---------------------------------------------------------------------------
__global__ __launch_bounds__(256) void setup_kernel(
    const float* __restrict__ wq, const float* __restrict__ wk,
    const float* __restrict__ wv,
    const float* __restrict__ bq, const float* __restrict__ bk,
    const float* __restrict__ bv,
    const float* __restrict__ w1_w, const float* __restrict__ w1_b,
    const float* __restrict__ w2_w, const float* __restrict__ w2_b,
    const float* __restrict__ w_bn1_g, const float* __restrict__ w_bn1_b,
    const float* __restrict__ w_bn1_m, const float* __restrict__ w_bn1_v,
    const float* __restrict__ w_bn2_g, const float* __restrict__ w_bn2_b,
    const float* __restrict__ w_bn2_m, const float* __restrict__ w_bn2_v,
    const float* __restrict__ p2_w, const float* __restrict__ p2_b,
    uint4* __restrict__ wtab, uint4* __restrict__ a1tab,
    uint2* __restrict__ a2tab, float* __restrict__ cz,
    float4* __restrict__ ctab, float4* __restrict__ ptab)
{
    const int t   = threadIdx.x;
    const int blk = blockIdx.x;
    {   // wtab: 6 blocks x 256 = 1536 entries
        int e = blk * 256 + t;
        int m = e >> 9, rem = e & 511;
        int og = rem >> 7, half = (rem >> 6) & 1, l = rem & 63;
        const float* W = (m == 0) ? wq : ((m == 1) ? wk : wv);
        const float* base = W + (size_t)(og * 16 + (l & 15)) * C_ + half * 32 + (l >> 4) * 8;
        uint4 o;
        o.x = packbf2(base[0], base[1]); o.y = packbf2(base[2], base[3]);
        o.z = packbf2(base[4], base[5]); o.w = packbf2(base[6], base[7]);
        wtab[e] = o;
    }
    if (blk == 0 && t < 128) {
        int half = t >> 6, l = t & 63;
        const float* base = w1_w + (size_t)(l & 15) * C_ + half * 32 + (l >> 4) * 8;
        uint4 o;
        o.x = packbf2(base[0], base[1]); o.y = packbf2(base[2], base[3]);
        o.z = packbf2(base[4], base[5]); o.w = packbf2(base[6], base[7]);
        a1tab[t] = o;
    }
    if (blk == 1 && t < 64) {
        const float* base = w2_w + (t & 15) * 16 + (t >> 4) * 4;
        uint2 o;
        o.x = packbf2(base[0], base[1]); o.y = packbf2(base[2], base[3]);
        a2tab[t] = o;
    }
    if (blk == 2 && t < 16) {
        float s = w_bn2_g[t] * rsqrtf(w_bn2_v[t] + EPS_);
        cz[t]      = s;
        cz[16 + t] = (w1_b[t] - w_bn2_m[t]) * s + w_bn2_b[t];
        cz[32 + t] = w2_b[t];
    }
    if (blk == 3 && t < 64) {
        float s   = w_bn1_g[t] * rsqrtf(w_bn1_v[t] + EPS_);
        float b1f = w_bn1_b[t] - w_bn1_m[t] * s;
        ctab[t] = float4{s, s * bq[t] - b1f, bk[t], bv[t]};
    }
    if (blk == 4 && t < 64) {
        ptab[t] = float4{p2_w[t*3+0], p2_w[t*3+1], p2_w[t*3+2], p2_b[t]};
    }
}

// ---------------------------------------------------------------------------
// Kernel A: projections + positional MLP + bn1 fold, MFMA (R10, unchanged).
// ---------------------------------------------------------------------------
__global__ __launch_bounds__(256) void proj_kernel(
    const float* __restrict__ q, const float* __restrict__ kin,
    const float* __restrict__ coord,
    const float* __restrict__ p1_w, const float* __restrict__ p1_b,
    const float* __restrict__ p_bn_g, const float* __restrict__ p_bn_b,
    const float* __restrict__ p_bn_m, const float* __restrict__ p_bn_v,
    const uint4* __restrict__ wtab,
    const float4* __restrict__ ctab, const float4* __restrict__ ptab,
    unsigned int* __restrict__ xq2, unsigned int* __restrict__ kv_t)
{
    constexpr int PS = 26;
    __shared__ unsigned int qp[32 * PS];
    __shared__ unsigned int kp[32 * PS];

    const int t   = threadIdx.x;
    const int og  = __builtin_amdgcn_readfirstlane(t >> 6);
    const int l   = t & 63;
    const int col = l & 15;
    const int qd  = l >> 4;
    const int pt0 = blockIdx.x * 16;
    const int pt  = pt0 + col;
    const int b   = pt0 / N_;
    const int n   = pt - b * N_;
    const size_t cb = (size_t)b * C_ * N_ + n;

#pragma unroll
    for (int r = 0; r < 2; r++) {
        int cp = (og << 3) + (qd << 1) + r;
        int ci = cp * 2;
        float q0 = q[cb + (size_t)ci * N_];
        float q1 = q[cb + (size_t)(ci + 1) * N_];
        float k0 = kin[cb + (size_t)ci * N_];
        float k1 = kin[cb + (size_t)(ci + 1) * N_];
        qp[cp * PS + col] = packbf2(q0, q1);
        kp[cp * PS + col] = packbf2(k0, k1);
    }

    union bf8u { bf16x8_t v; uint4 u4; };
    bf8u awq[2], awk[2], awv[2];
#pragma unroll
    for (int half = 0; half < 2; half++) {
        awq[half].u4 = wtab[0 * 512 + og * 128 + half * 64 + l];
        awk[half].u4 = wtab[1 * 512 + og * 128 + half * 64 + l];
        awv[half].u4 = wtab[2 * 512 + og * 128 + half * 64 + l];
    }

    __syncthreads();

    union bf8b { bf16x8_t v; unsigned int u[4]; };
    bf8b bq_[2], bk_[2];
#pragma unroll
    for (int half = 0; half < 2; half++) {
#pragma unroll
        for (int i2 = 0; i2 < 4; i2++) {
            int cp = half * 16 + qd * 4 + i2;
            bq_[half].u[i2] = qp[cp * PS + col];
            bk_[half].u[i2] = kp[cp * PS + col];
        }
    }

    f32x4_t uq = {0.f, 0.f, 0.f, 0.f};
    f32x4_t uv = {0.f, 0.f, 0.f, 0.f};
    f32x4_t uk = {0.f, 0.f, 0.f, 0.f};
    uq = __builtin_amdgcn_mfma_f32_16x16x32_bf16(awq[0].v, bq_[0].v, uq, 0, 0, 0);
    uq = __builtin_amdgcn_mfma_f32_16x16x32_bf16(awq[1].v, bq_[1].v, uq, 0, 0, 0);
    uv = __builtin_amdgcn_mfma_f32_16x16x32_bf16(awv[0].v, bq_[0].v, uv, 0, 0, 0);
    uv = __builtin_amdgcn_mfma_f32_16x16x32_bf16(awv[1].v, bq_[1].v, uv, 0, 0, 0);
    uk = __builtin_amdgcn_mfma_f32_16x16x32_bf16(awk[0].v, bk_[0].v, uk, 0, 0, 0);
    uk = __builtin_amdgcn_mfma_f32_16x16x32_bf16(awk[1].v, bk_[1].v, uk, 0, 0, 0);

    float pbs[3], pbb[3];
#pragma unroll
    for (int j = 0; j < 3; j++) {
        float s = p_bn_g[j] * rsqrtf(p_bn_v[j] + EPS_);
        pbs[j] = s;
        pbb[j] = (p1_b[j] - p_bn_m[j]) * s + p_bn_b[j];
    }
    float cx = coord[pt * 3 + 0], cy = coord[pt * 3 + 1], cz = coord[pt * 3 + 2];
    float h0 = fmaxf(0.f, (p1_w[0]*cx + p1_w[1]*cy + p1_w[2]*cz) * pbs[0] + pbb[0]);
    float h1 = fmaxf(0.f, (p1_w[3]*cx + p1_w[4]*cy + p1_w[5]*cz) * pbs[1] + pbb[1]);
    float h2 = fmaxf(0.f, (p1_w[6]*cx + p1_w[7]*cy + p1_w[8]*cz) * pbs[2] + pbb[2]);

    const int ch0 = og * 16 + qd * 4;
    float xv2[4];
    uint4 kvo;
#pragma unroll
    for (int rr = 0; rr < 4; rr++) {
        const float4 ct  = ctab[ch0 + rr];
        const float4 pt4 = ptab[ch0 + rr];
        float pos = fmaf(pt4.x, h0, fmaf(pt4.y, h1, fmaf(pt4.z, h2, pt4.w)));
        xv2[rr]   = fmaf(ct.x, uq[rr], ct.y);
        float kk  = ct.x * (uk[rr] + ct.z + pos);
        float vv  = uv[rr] + ct.w + pos;
        (&kvo.x)[rr] = packbf2(kk, vv);
    }
    uint2 xqo;
    xqo.x = packbf2(xv2[0], xv2[1]);
    xqo.y = packbf2(xv2[2], xv2[3]);
    *reinterpret_cast<uint2*>(xq2 + (size_t)pt * 32 + (ch0 >> 1)) = xqo;
    *reinterpret_cast<uint4*>(kv_t + (size_t)pt * C_ + ch0) = kvo;
}

// ---------------------------------------------------------------------------
// Kernel B: attention via MFMA, 2 tiles per block with cross-tile gather
// prefetch (T14 issue-early/consume-late: tile B's 8 gathers + xq load are
// issued before tile A's compute, hiding ~400-900cyc of gather latency
// under tile A's ~400cyc compute phase). 512 thr = 8 waves; block handles
// 16 consecutive points as tiles A (8) and B (8). LDS 30976B -> 4 blk/CU
// (wave-limit), per-wave LDS buffers reused in-order across tiles.
// ---------------------------------------------------------------------------
#define WROW 72          // ushorts per w-tile row (144B)
#define WPN  (K_ * WROW) // 1152 per point
#define SS4  20          // sfb row stride (f32)
#define SPN  (K_ * SS4)  // 320 per point

__global__ __launch_bounds__(512, 8) void attn_kernel(
    const int* __restrict__ nbr,
    const unsigned int* __restrict__ xq2, const unsigned int* __restrict__ kv_t,
    const uint4* __restrict__ a1tab, const uint2* __restrict__ a2tab,
    const float* __restrict__ cz,
    float* __restrict__ out)
{
    __shared__ unsigned short wlds_all[8 * WPN];   // 18432B
    __shared__ float          sfb_all[8 * SPN];    // 10240B
    __shared__ float          otile[64 * 9];       //  2304B

    const int t  = threadIdx.x;
    const int w  = __builtin_amdgcn_readfirstlane(t >> 6);
    const int l  = t & 63;
    const int al = l & 15;
    const int qd = l >> 4;
    const int cpair = l & 31;
    const int kh    = l >> 5;
    const int c0    = cpair * 2;

    const int pt0A = blockIdx.x * 16;     // 2500 blocks; 20000%16==0, no straddle
    const int b    = pt0A / N_;
    const int bB   = b * N_;
    const int bnA  = pt0A + w;
    const int bnB  = pt0A + 8 + w;

    unsigned short* wlds = wlds_all + w * WPN;
    float*          sfb  = sfb_all + w * SPN;

    // ---- issue ALL gathers for both tiles up front ----
    const int* nbA = nbr + (size_t)bnA * K_;
    const int* nbB = nbr + (size_t)bnB * K_;
    uint2 kvwA[8], kvwB[8];
#pragma unroll
    for (int j = 0; j < 8; j++) {
        int ia = nbA[j], ib = nbA[8 + j];           // wave-uniform -> s_load
        int idx = (kh != 0) ? ib : ia;
        kvwA[j] = *reinterpret_cast<const uint2*>(kv_t + ((size_t)(bB + idx) * C_ + c0));
    }
#pragma unroll
    for (int j = 0; j < 8; j++) {
        int ia = nbB[j], ib = nbB[8 + j];
        int idx = (kh != 0) ? ib : ia;
        kvwB[j] = *reinterpret_cast<const uint2*>(kv_t + ((size_t)(bB + idx) * C_ + c0));
    }
    const unsigned int xquA = xq2[(size_t)bnA * 32 + cpair];
    const unsigned int xquB = xq2[(size_t)bnB * 32 + cpair];

    // constants from tables
    union bf8u { bf16x8_t v; uint4 u4; };
    union bf4u { bf16x4_t v; uint2 u2; };
    bf8u a1q0, a1q1; bf4u a2q;
    a1q0.u4 = a1tab[l];
    a1q1.u4 = a1tab[64 + l];
    a2q.u2  = a2tab[l];
    const float4 zsc4 = *reinterpret_cast<const float4*>(cz + qd * 4);
    const float4 zbi4 = *reinterpret_cast<const float4*>(cz + 16 + qd * 4);
    const float4 tbi4 = *reinterpret_cast<const float4*>(cz + 32 + qd * 4);
    const int g0 = c0 & 15;

    // ================= tile A =================
    {
        const float xq0 = bf_lo(xquA), xq1 = bf_hi(xquA);
#pragma unroll
        for (int j = 0; j < 8; j++) {
            float w0 = fmaxf(0.f, bf_lo(kvwA[j].x) - xq0);
            float w1 = fmaxf(0.f, bf_lo(kvwA[j].y) - xq1);
            *reinterpret_cast<unsigned int*>(wlds + (kh * 8 + j) * WROW + c0) = packbf2(w0, w1);
        }
        wave_fence();

        const bf16x8_t b0 = *reinterpret_cast<const bf16x8_t*>(wlds + al * WROW + qd * 8);
        const bf16x8_t b1 = *reinterpret_cast<const bf16x8_t*>(wlds + al * WROW + 32 + qd * 8);
        f32x4_t u = {0.f, 0.f, 0.f, 0.f};
        u = __builtin_amdgcn_mfma_f32_16x16x32_bf16(a1q0.v, b0, u, 0, 0, 0);
        u = __builtin_amdgcn_mfma_f32_16x16x32_bf16(a1q1.v, b1, u, 0, 0, 0);

        union { bf16x4_t v; unsigned int u2[2]; } zb;
        {
            float z0 = fmaxf(0.f, u[0] * zsc4.x + zbi4.x);
            float z1 = fmaxf(0.f, u[1] * zsc4.y + zbi4.y);
            float z2 = fmaxf(0.f, u[2] * zsc4.z + zbi4.z);
            float z3 = fmaxf(0.f, u[3] * zsc4.w + zbi4.w);
            zb.u2[0] = packbf2(z0, z1);
            zb.u2[1] = packbf2(z2, z3);
        }
        f32x4_t t4 = {0.f, 0.f, 0.f, 0.f};
        t4 = __builtin_amdgcn_mfma_f32_16x16x16bf16_1k(a2q.v, zb.v, t4, 0, 0, 0);

        float4 sv;
#pragma unroll
        for (int rr = 0; rr < 4; rr++) {
            float e = __expf(t4[rr] + (&tbi4.x)[rr]);   // |t| << 80
            float s = e;
            s += __shfl_xor(s, 1);
            s += __shfl_xor(s, 2);
            s += __shfl_xor(s, 4);
            s += __shfl_xor(s, 8);
            (&sv.x)[rr] = e * __builtin_amdgcn_rcpf(s);
        }
        *reinterpret_cast<float4*>(sfb + al * SS4 + qd * 4) = sv;
        wave_fence();

        float acc0 = 0.f, acc1 = 0.f;
#pragma unroll
        for (int j = 0; j < 8; j++) {
            float2 sp = *reinterpret_cast<const float2*>(sfb + (kh * 8 + j) * SS4 + g0);
            acc0 = fmaf(bf_hi(kvwA[j].x), sp.x, acc0);
            acc1 = fmaf(bf_hi(kvwA[j].y), sp.y, acc1);
        }
        acc0 += __shfl_xor(acc0, 32);
        acc1 += __shfl_xor(acc1, 32);
        if (kh == 0) {
            otile[c0 * 9 + w]       = acc0;
            otile[(c0 + 1) * 9 + w] = acc1;
        }
    }
    __syncthreads();
    {   // coalesced [B,C,N] write, tile A
        int c  = t >> 3;
        int nn = t & 7;
        out[(size_t)b * C_ * N_ + (size_t)c * N_ + (pt0A - bB) + nn] = otile[c * 9 + nn];
    }
    __syncthreads();   // otile reads done before tile B writes

    // ================= tile B =================
    {
        const float xq0 = bf_lo(xquB), xq1 = bf_hi(xquB);
#pragma unroll
        for (int j = 0; j < 8; j++) {
            float w0 = fmaxf(0.f, bf_lo(kvwB[j].x) - xq0);
            float w1 = fmaxf(0.f, bf_lo(kvwB[j].y) - xq1);
            *reinterpret_cast<unsigned int*>(wlds + (kh * 8 + j) * WROW + c0) = packbf2(w0, w1);
        }
        wave_fence();

        const bf16x8_t b0 = *reinterpret_cast<const bf16x8_t*>(wlds + al * WROW + qd * 8);
        const bf16x8_t b1 = *reinterpret_cast<const bf16x8_t*>(wlds + al * WROW + 32 + qd * 8);
        f32x4_t u = {0.f, 0.f, 0.f, 0.f};
        u = __builtin_amdgcn_mfma_f32_16x16x32_bf16(a1q0.v, b0, u, 0, 0, 0);
        u = __builtin_amdgcn_mfma_f32_16x16x32_bf16(a1q1.v, b1, u, 0, 0, 0);

        union { bf16x4_t v; unsigned int u2[2]; } zb;
        {
            float z0 = fmaxf(0.f, u[0] * zsc4.x + zbi4.x);
            float z1 = fmaxf(0.f, u[1] * zsc4.y + zbi4.y);
            float z2 = fmaxf(0.f, u[2] * zsc4.z + zbi4.z);
            float z3 = fmaxf(0.f, u[3] * zsc4.w + zbi4.w);
            zb.u2[0] = packbf2(z0, z1);
            zb.u2[1] = packbf2(z2, z3);
        }
        f32x4_t t4 = {0.f, 0.f, 0.f, 0.f};
        t4 = __builtin_amdgcn_mfma_f32_16x16x16bf16_1k(a2q.v, zb.v, t4, 0, 0, 0);

        float4 sv;
#pragma unroll
        for (int rr = 0; rr < 4; rr++) {
            float e = __expf(t4[rr] + (&tbi4.x)[rr]);
            float s = e;
            s += __shfl_xor(s, 1);
            s += __shfl_xor(s, 2);
            s += __shfl_xor(s, 4);
            s += __shfl_xor(s, 8);
            (&sv.x)[rr] = e * __builtin_amdgcn_rcpf(s);
        }
        *reinterpret_cast<float4*>(sfb + al * SS4 + qd * 4) = sv;
        wave_fence();

        float acc0 = 0.f, acc1 = 0.f;
#pragma unroll
        for (int j = 0; j < 8; j++) {
            float2 sp = *reinterpret_cast<const float2*>(sfb + (kh * 8 + j) * SS4 + g0);
            acc0 = fmaf(bf_hi(kvwB[j].x), sp.x, acc0);
            acc1 = fmaf(bf_hi(kvwB[j].y), sp.y, acc1);
        }
        acc0 += __shfl_xor(acc0, 32);
        acc1 += __shfl_xor(acc1, 32);
        if (kh == 0) {
            otile[c0 * 9 + w]       = acc0;
            otile[(c0 + 1) * 9 + w] = acc1;
        }
    }
    __syncthreads();
    {   // coalesced [B,C,N] write, tile B
        int c  = t >> 3;
        int nn = t & 7;
        out[(size_t)b * C_ * N_ + (size_t)c * N_ + (pt0A + 8 - bB) + nn] = otile[c * 9 + nn];
    }
}

// ---------------------------------------------------------------------------
extern "C" void kernel_launch(void* const* d_in, const int* in_sizes, int n_in,
                              void* d_out, int out_size, void* d_ws, size_t ws_size,
                              hipStream_t stream)
{
    const float* coord = (const float*)d_in[0];
    const float* q     = (const float*)d_in[1];
    const float* k     = (const float*)d_in[2];
    const int*   nbr   = (const int*)d_in[3];
    const float* wq = (const float*)d_in[4];
    const float* bq = (const float*)d_in[5];
    const float* wk = (const float*)d_in[6];
    const float* bk = (const float*)d_in[7];
    const float* wv = (const float*)d_in[8];
    const float* bv = (const float*)d_in[9];
    const float* p1_w = (const float*)d_in[10];
    const float* p1_b = (const float*)d_in[11];
    const float* p_bn_g = (const float*)d_in[12];
    const float* p_bn_b = (const float*)d_in[13];
    const float* p_bn_m = (const float*)d_in[14];
    const float* p_bn_v = (const float*)d_in[15];
    const float* p2_w = (const float*)d_in[16];
    const float* p2_b = (const float*)d_in[17];
    const float* w_bn1_g = (const float*)d_in[18];
    const float* w_bn1_b = (const float*)d_in[19];
    const float* w_bn1_m = (const float*)d_in[20];
    const float* w_bn1_v = (const float*)d_in[21];
    const float* w1_w = (const float*)d_in[22];
    const float* w1_b = (const float*)d_in[23];
    const float* w_bn2_g = (const float*)d_in[24];
    const float* w_bn2_b = (const float*)d_in[25];
    const float* w_bn2_m = (const float*)d_in[26];
    const float* w_bn2_v = (const float*)d_in[27];
    const float* w2_w = (const float*)d_in[28];
    const float* w2_b = (const float*)d_in[29];

    const size_t PTS = (size_t)B_ * N_;        // 40000
    char* wsb = (char*)d_ws;
    unsigned int* kv_t = (unsigned int*)wsb;                    // [PTS][64] u32 (10.24MB)
    unsigned int* xq2  = (unsigned int*)(wsb + PTS * C_ * 4);   // [PTS][32] u32 (5.12MB)
    uint4* wtab  = (uint4*)(wsb + PTS * C_ * 4 + PTS * C_ * 2); // 1536 uint4
    uint4* a1tab = wtab + 1536;                                 // 128 uint4
    uint2* a2tab = (uint2*)(a1tab + 128);                       // 64 uint2
    float* cz    = (float*)(a2tab + 64);                        // 48 f32
    float4* ctab = (float4*)(cz + 48);                          // 64 float4
    float4* ptab = ctab + 64;                                   // 64 float4

    setup_kernel<<<6, 256, 0, stream>>>(
        wq, wk, wv, bq, bk, bv, w1_w, w1_b, w2_w, w2_b,
        w_bn1_g, w_bn1_b, w_bn1_m, w_bn1_v,
        w_bn2_g, w_bn2_b, w_bn2_m, w_bn2_v,
        p2_w, p2_b,
        wtab, a1tab, a2tab, cz, ctab, ptab);

    proj_kernel<<<(B_ * N_) / 16, 256, 0, stream>>>(
        q, k, coord,
        p1_w, p1_b, p_bn_g, p_bn_b, p_bn_m, p_bn_v,
        wtab, ctab, ptab, xq2, kv_t);

    attn_kernel<<<(B_ * N_) / 16, 512, 0, stream>>>(
        nbr, xq2, kv_t, a1tab, a2tab, cz,
        (float*)d_out);
}

// Round 13
// 44.607 us; speedup vs baseline: 4.7446x; 1.7418x over previous
//
#include <hip/hip_runtime.h>
#include <hip/hip_bf16.h>
#include <math.h>

#define B_ 2
#define N_ 20000
#define C_ 64
#define K_ 16
#define CS_ 16
#define EPS_ 1e-5f

typedef float f32x4_t  __attribute__((ext_vector_type(4)));
typedef short bf16x8_t __attribute__((ext_vector_type(8)));
typedef short bf16x4_t __attribute__((ext_vector_type(4)));

__device__ __forceinline__ unsigned int packbf2(float a, float b)
{
    union { __hip_bfloat162 h; unsigned int u; } cv;
    cv.h = __float22bfloat162_rn(float2{a, b});
    return cv.u;
}
__device__ __forceinline__ float bf_lo(unsigned int w)
{
    return __builtin_bit_cast(float, w << 16);
}
__device__ __forceinline__ float bf_hi(unsigned int w)
{
    return __builtin_bit_cast(float, w & 0xFFFF0000u);
}
__device__ __forceinline__ void wave_fence()
{
    __builtin_amdgcn_wave_barrier();
}

// DPP rotate-reduce over each 16-lane row (VALU pipe, not DS).
// After ror 8,4,2,1 every lane holds the row sum.
__device__ __forceinline__ float row_sum16(float x)
{
    float s = x;
    s += __builtin_bit_cast(float, __builtin_amdgcn_update_dpp(
            0, __builtin_bit_cast(int, s), 0x128, 0xF, 0xF, false)); // row_ror:8
    s += __builtin_bit_cast(float, __builtin_amdgcn_update_dpp(
            0, __builtin_bit_cast(int, s), 0x124, 0xF, 0xF, false)); // row_ror:4
    s += __builtin_bit_cast(float, __builtin_amdgcn_update_dpp(
            0, __builtin_bit_cast(int, s), 0x122, 0xF, 0xF, false)); // row_ror:2
    s += __builtin_bit_cast(float, __builtin_amdgcn_update_dpp(
            0, __builtin_bit_cast(int, s), 0x121, 0xF, 0xF, false)); // row_ror:1
    return s;
}

// ---------------------------------------------------------------------------
// Kernel 0: setup, 6 blocks, disjoint work (R10, unchanged).
// ---------------------------------------------------------------------------
__global__ __launch_bounds__(256) void setup_kernel(
    const float* __restrict__ wq, const float* __restrict__ wk,
    const float* __restrict__ wv,
    const float* __restrict__ bq, const float* __restrict__ bk,
    const float* __restrict__ bv,
    const float* __restrict__ w1_w, const float* __restrict__ w1_b,
    const float* __restrict__ w2_w, const float* __restrict__ w2_b,
    const float* __restrict__ w_bn1_g, const float* __restrict__ w_bn1_b,
    const float* __restrict__ w_bn1_m, const float* __restrict__ w_bn1_v,
    const float* __restrict__ w_bn2_g, const float* __restrict__ w_bn2_b,
    const float* __restrict__ w_bn2_m, const float* __restrict__ w_bn2_v,
    const float* __restrict__ p2_w, const float* __restrict__ p2_b,
    uint4* __restrict__ wtab, uint4* __restrict__ a1tab,
    uint2* __restrict__ a2tab, float* __restrict__ cz,
    float4* __restrict__ ctab, float4* __restrict__ ptab)
{
    const int t   = threadIdx.x;
    const int blk = blockIdx.x;
    {
        int e = blk * 256 + t;
        int m = e >> 9, rem = e & 511;
        int og = rem >> 7, half = (rem >> 6) & 1, l = rem & 63;
        const float* W = (m == 0) ? wq : ((m == 1) ? wk : wv);
        const float* base = W + (size_t)(og * 16 + (l & 15)) * C_ + half * 32 + (l >> 4) * 8;
        uint4 o;
        o.x = packbf2(base[0], base[1]); o.y = packbf2(base[2], base[3]);
        o.z = packbf2(base[4], base[5]); o.w = packbf2(base[6], base[7]);
        wtab[e] = o;
    }
    if (blk == 0 && t < 128) {
        int half = t >> 6, l = t & 63;
        const float* base = w1_w + (size_t)(l & 15) * C_ + half * 32 + (l >> 4) * 8;
        uint4 o;
        o.x = packbf2(base[0], base[1]); o.y = packbf2(base[2], base[3]);
        o.z = packbf2(base[4], base[5]); o.w = packbf2(base[6], base[7]);
        a1tab[t] = o;
    }
    if (blk == 1 && t < 64) {
        const float* base = w2_w + (t & 15) * 16 + (t >> 4) * 4;
        uint2 o;
        o.x = packbf2(base[0], base[1]); o.y = packbf2(base[2], base[3]);
        a2tab[t] = o;
    }
    if (blk == 2 && t < 16) {
        float s = w_bn2_g[t] * rsqrtf(w_bn2_v[t] + EPS_);
        cz[t]      = s;
        cz[16 + t] = (w1_b[t] - w_bn2_m[t]) * s + w_bn2_b[t];
        cz[32 + t] = w2_b[t];
    }
    if (blk == 3 && t < 64) {
        float s   = w_bn1_g[t] * rsqrtf(w_bn1_v[t] + EPS_);
        float b1f = w_bn1_b[t] - w_bn1_m[t] * s;
        ctab[t] = float4{s, s * bq[t] - b1f, bk[t], bv[t]};
    }
    if (blk == 4 && t < 64) {
        ptab[t] = float4{p2_w[t*3+0], p2_w[t*3+1], p2_w[t*3+2], p2_b[t]};
    }
}

// ---------------------------------------------------------------------------
// Kernel A: projections + positional MLP + bn1 fold, MFMA (R10, unchanged).
// ---------------------------------------------------------------------------
__global__ __launch_bounds__(256) void proj_kernel(
    const float* __restrict__ q, const float* __restrict__ kin,
    const float* __restrict__ coord,
    const float* __restrict__ p1_w, const float* __restrict__ p1_b,
    const float* __restrict__ p_bn_g, const float* __restrict__ p_bn_b,
    const float* __restrict__ p_bn_m, const float* __restrict__ p_bn_v,
    const uint4* __restrict__ wtab,
    const float4* __restrict__ ctab, const float4* __restrict__ ptab,
    unsigned int* __restrict__ xq2, unsigned int* __restrict__ kv_t)
{
    constexpr int PS = 26;
    __shared__ unsigned int qp[32 * PS];
    __shared__ unsigned int kp[32 * PS];

    const int t   = threadIdx.x;
    const int og  = __builtin_amdgcn_readfirstlane(t >> 6);
    const int l   = t & 63;
    const int col = l & 15;
    const int qd  = l >> 4;
    const int pt0 = blockIdx.x * 16;
    const int pt  = pt0 + col;
    const int b   = pt0 / N_;
    const int n   = pt - b * N_;
    const size_t cb = (size_t)b * C_ * N_ + n;

#pragma unroll
    for (int r = 0; r < 2; r++) {
        int cp = (og << 3) + (qd << 1) + r;
        int ci = cp * 2;
        float q0 = q[cb + (size_t)ci * N_];
        float q1 = q[cb + (size_t)(ci + 1) * N_];
        float k0 = kin[cb + (size_t)ci * N_];
        float k1 = kin[cb + (size_t)(ci + 1) * N_];
        qp[cp * PS + col] = packbf2(q0, q1);
        kp[cp * PS + col] = packbf2(k0, k1);
    }

    union bf8u { bf16x8_t v; uint4 u4; };
    bf8u awq[2], awk[2], awv[2];
#pragma unroll
    for (int half = 0; half < 2; half++) {
        awq[half].u4 = wtab[0 * 512 + og * 128 + half * 64 + l];
        awk[half].u4 = wtab[1 * 512 + og * 128 + half * 64 + l];
        awv[half].u4 = wtab[2 * 512 + og * 128 + half * 64 + l];
    }

    __syncthreads();

    union bf8b { bf16x8_t v; unsigned int u[4]; };
    bf8b bq_[2], bk_[2];
#pragma unroll
    for (int half = 0; half < 2; half++) {
#pragma unroll
        for (int i2 = 0; i2 < 4; i2++) {
            int cp = half * 16 + qd * 4 + i2;
            bq_[half].u[i2] = qp[cp * PS + col];
            bk_[half].u[i2] = kp[cp * PS + col];
        }
    }

    f32x4_t uq = {0.f, 0.f, 0.f, 0.f};
    f32x4_t uv = {0.f, 0.f, 0.f, 0.f};
    f32x4_t uk = {0.f, 0.f, 0.f, 0.f};
    uq = __builtin_amdgcn_mfma_f32_16x16x32_bf16(awq[0].v, bq_[0].v, uq, 0, 0, 0);
    uq = __builtin_amdgcn_mfma_f32_16x16x32_bf16(awq[1].v, bq_[1].v, uq, 0, 0, 0);
    uv = __builtin_amdgcn_mfma_f32_16x16x32_bf16(awv[0].v, bq_[0].v, uv, 0, 0, 0);
    uv = __builtin_amdgcn_mfma_f32_16x16x32_bf16(awv[1].v, bq_[1].v, uv, 0, 0, 0);
    uk = __builtin_amdgcn_mfma_f32_16x16x32_bf16(awk[0].v, bk_[0].v, uk, 0, 0, 0);
    uk = __builtin_amdgcn_mfma_f32_16x16x32_bf16(awk[1].v, bk_[1].v, uk, 0, 0, 0);

    float pbs[3], pbb[3];
#pragma unroll
    for (int j = 0; j < 3; j++) {
        float s = p_bn_g[j] * rsqrtf(p_bn_v[j] + EPS_);
        pbs[j] = s;
        pbb[j] = (p1_b[j] - p_bn_m[j]) * s + p_bn_b[j];
    }
    float cx = coord[pt * 3 + 0], cy = coord[pt * 3 + 1], cz = coord[pt * 3 + 2];
    float h0 = fmaxf(0.f, (p1_w[0]*cx + p1_w[1]*cy + p1_w[2]*cz) * pbs[0] + pbb[0]);
    float h1 = fmaxf(0.f, (p1_w[3]*cx + p1_w[4]*cy + p1_w[5]*cz) * pbs[1] + pbb[1]);
    float h2 = fmaxf(0.f, (p1_w[6]*cx + p1_w[7]*cy + p1_w[8]*cz) * pbs[2] + pbb[2]);

    const int ch0 = og * 16 + qd * 4;
    float xv2[4];
    uint4 kvo;
#pragma unroll
    for (int rr = 0; rr < 4; rr++) {
        const float4 ct  = ctab[ch0 + rr];
        const float4 pt4 = ptab[ch0 + rr];
        float pos = fmaf(pt4.x, h0, fmaf(pt4.y, h1, fmaf(pt4.z, h2, pt4.w)));
        xv2[rr]   = fmaf(ct.x, uq[rr], ct.y);
        float kk  = ct.x * (uk[rr] + ct.z + pos);
        float vv  = uv[rr] + ct.w + pos;
        (&kvo.x)[rr] = packbf2(kk, vv);
    }
    uint2 xqo;
    xqo.x = packbf2(xv2[0], xv2[1]);
    xqo.y = packbf2(xv2[2], xv2[3]);
    *reinterpret_cast<uint2*>(xq2 + (size_t)pt * 32 + (ch0 >> 1)) = xqo;
    *reinterpret_cast<uint4*>(kv_t + (size_t)pt * C_ + ch0) = kvo;
}

// ---------------------------------------------------------------------------
// Kernel B: attention via MFMA — DS-pipe-lean version.
// Block = 512 thr = 8 waves = 8 points (R10 structure, no cross-tile prefetch).
// Phase1/3 lane roles: cquad = l&15 (4 channels c0=4*cquad), kq = l>>4
//   (4 neighbors k = 4*kq+j): 4x dwordx4 gathers (16B/lane), 4x ds_write_b64.
// Phase2 roles (al,qd): 2x mfma 16x16x32, bn2/relu in regs, 1x mfma 16x16x16.
// Softmax sum over 16 lanes via DPP row_ror rotate-reduce (VALU pipe).
// Phase3: 4x ds_read_b128 sfb rows, 4-ch partials, shfl_xor(16/32) combine.
// DS ops/wave ~21 (was ~42). LDS 30848B -> 4 blocks/CU = 32 waves/CU.
// ---------------------------------------------------------------------------
#define WROW 72          // ushorts per w-tile row (144B)
#define WPN  (K_ * WROW) // 1152 per point
#define SS4  20          // sfb row stride (f32)
#define SPN  (K_ * SS4)  // 320 per point
#define OS   68          // otile row stride (f32)

__global__ __launch_bounds__(512, 8) void attn_kernel(
    const int* __restrict__ nbr,
    const unsigned int* __restrict__ xq2, const unsigned int* __restrict__ kv_t,
    const uint4* __restrict__ a1tab, const uint2* __restrict__ a2tab,
    const float* __restrict__ cz,
    float* __restrict__ out)
{
    __shared__ unsigned short wlds_all[8 * WPN];   // 18432B
    __shared__ float          sfb_all[8 * SPN];    // 10240B
    __shared__ float          otile[8 * OS];       //  2176B

    const int t  = threadIdx.x;
    const int w  = __builtin_amdgcn_readfirstlane(t >> 6);
    const int l  = t & 63;
    const int al = l & 15;          // phase-2 / neighbor-col role
    const int qd = l >> 4;          // phase-2 row-quad
    const int cquad = al;           // phase-1/3: 4 channels c0..c0+3
    const int kq    = qd;           // phase-1/3: 4 neighbors 4kq..4kq+3
    const int c0    = cquad * 4;
    const int g0    = c0 & 15;

    const int pt0 = blockIdx.x * 8;       // 5000 blocks; 20000%8==0, no straddle
    const int b   = pt0 / N_;
    const int bB  = b * N_;
    const int bn  = pt0 + w;

    unsigned short* wlds = wlds_all + w * WPN;
    float*          sfb  = sfb_all + w * SPN;

    // ---- phase 1: gather 4 neighbors x 4 channels (dwordx4, 16B/lane) ----
    const int* nb = nbr + (size_t)bn * K_;
    uint4 kvw[4];
#pragma unroll
    for (int j = 0; j < 4; j++) {
        int idx = nb[kq * 4 + j];          // wave-uniform -> s_load
        kvw[j] = *reinterpret_cast<const uint4*>(kv_t + ((size_t)(bB + idx) * C_ + c0));
    }
    const uint2 xqu = *reinterpret_cast<const uint2*>(xq2 + (size_t)bn * 32 + (c0 >> 1));
    const float xqa = bf_lo(xqu.x), xqb = bf_hi(xqu.x);
    const float xqc = bf_lo(xqu.y), xqd = bf_hi(xqu.y);

    // constants from tables
    union bf8u { bf16x8_t v; uint4 u4; };
    union bf4u { bf16x4_t v; uint2 u2; };
    bf8u a1q0, a1q1; bf4u a2q;
    a1q0.u4 = a1tab[l];
    a1q1.u4 = a1tab[64 + l];
    a2q.u2  = a2tab[l];
    const float4 zsc4 = *reinterpret_cast<const float4*>(cz + qd * 4);
    const float4 zbi4 = *reinterpret_cast<const float4*>(cz + 16 + qd * 4);
    const float4 tbi4 = *reinterpret_cast<const float4*>(cz + 32 + qd * 4);

    // w = relu(kvlo - xq2), packed pairs -> one ds_write_b64 per neighbor
#pragma unroll
    for (int j = 0; j < 4; j++) {
        float w0 = fmaxf(0.f, bf_lo(kvw[j].x) - xqa);
        float w1 = fmaxf(0.f, bf_lo(kvw[j].y) - xqb);
        float w2 = fmaxf(0.f, bf_lo(kvw[j].z) - xqc);
        float w3 = fmaxf(0.f, bf_lo(kvw[j].w) - xqd);
        uint2 wpk;
        wpk.x = packbf2(w0, w1);
        wpk.y = packbf2(w2, w3);
        *reinterpret_cast<uint2*>(wlds + (kq * 4 + j) * WROW + c0) = wpk;
    }
    wave_fence();

    // ---- phase 2a: u = w1 @ w^T ----
    const bf16x8_t b0 = *reinterpret_cast<const bf16x8_t*>(wlds + al * WROW + qd * 8);
    const bf16x8_t b1 = *reinterpret_cast<const bf16x8_t*>(wlds + al * WROW + 32 + qd * 8);
    f32x4_t u = {0.f, 0.f, 0.f, 0.f};
    u = __builtin_amdgcn_mfma_f32_16x16x32_bf16(a1q0.v, b0, u, 0, 0, 0);
    u = __builtin_amdgcn_mfma_f32_16x16x32_bf16(a1q1.v, b1, u, 0, 0, 0);

    union { bf16x4_t v; unsigned int u2[2]; } zb;
    {
        float z0 = fmaxf(0.f, u[0] * zsc4.x + zbi4.x);
        float z1 = fmaxf(0.f, u[1] * zsc4.y + zbi4.y);
        float z2 = fmaxf(0.f, u[2] * zsc4.z + zbi4.z);
        float z3 = fmaxf(0.f, u[3] * zsc4.w + zbi4.w);
        zb.u2[0] = packbf2(z0, z1);
        zb.u2[1] = packbf2(z2, z3);
    }

    // ---- phase 2b: t = w2 @ z ----
    f32x4_t t4 = {0.f, 0.f, 0.f, 0.f};
    t4 = __builtin_amdgcn_mfma_f32_16x16x16bf16_1k(a2q.v, zb.v, t4, 0, 0, 0);

    // ---- softmax over neighbors: DPP rotate-reduce (VALU, not DS) ----
    float4 sv;
#pragma unroll
    for (int rr = 0; rr < 4; rr++) {
        float e = __expf(t4[rr] + (&tbi4.x)[rr]);   // |t| << 80, no max-sub
        float s = row_sum16(e);
        (&sv.x)[rr] = e * __builtin_amdgcn_rcpf(s);
    }
    *reinterpret_cast<float4*>(sfb + al * SS4 + qd * 4) = sv;  // [k][g] row al
    wave_fence();

    // ---- phase 3: out[c] = sum_k v[k][c] * soft[k][c&15] ----
    float acc[4] = {0.f, 0.f, 0.f, 0.f};
#pragma unroll
    for (int j = 0; j < 4; j++) {
        const float4 sp = *reinterpret_cast<const float4*>(sfb + (kq * 4 + j) * SS4 + g0);
        acc[0] = fmaf(bf_hi(kvw[j].x), sp.x, acc[0]);
        acc[1] = fmaf(bf_hi(kvw[j].y), sp.y, acc[1]);
        acc[2] = fmaf(bf_hi(kvw[j].z), sp.z, acc[2]);
        acc[3] = fmaf(bf_hi(kvw[j].w), sp.w, acc[3]);
    }
#pragma unroll
    for (int i = 0; i < 4; i++) {
        acc[i] += __shfl_xor(acc[i], 16);
        acc[i] += __shfl_xor(acc[i], 32);
    }
    if (kq == 0) {
        float4 o4 = float4{acc[0], acc[1], acc[2], acc[3]};
        *reinterpret_cast<float4*>(otile + w * OS + c0) = o4;
    }
    __syncthreads();

    // coalesced [B,C,N] write: thread t -> (c = t>>3, n = pt0%N + (t&7))
    {
        int c  = t >> 3;
        int nn = t & 7;
        out[(size_t)b * C_ * N_ + (size_t)c * N_ + (pt0 - bB) + nn] = otile[nn * OS + c];
    }
}

// ---------------------------------------------------------------------------
extern "C" void kernel_launch(void* const* d_in, const int* in_sizes, int n_in,
                              void* d_out, int out_size, void* d_ws, size_t ws_size,
                              hipStream_t stream)
{
    const float* coord = (const float*)d_in[0];
    const float* q     = (const float*)d_in[1];
    const float* k     = (const float*)d_in[2];
    const int*   nbr   = (const int*)d_in[3];
    const float* wq = (const float*)d_in[4];
    const float* bq = (const float*)d_in[5];
    const float* wk = (const float*)d_in[6];
    const float* bk = (const float*)d_in[7];
    const float* wv = (const float*)d_in[8];
    const float* bv = (const float*)d_in[9];
    const float* p1_w = (const float*)d_in[10];
    const float* p1_b = (const float*)d_in[11];
    const float* p_bn_g = (const float*)d_in[12];
    const float* p_bn_b = (const float*)d_in[13];
    const float* p_bn_m = (const float*)d_in[14];
    const float* p_bn_v = (const float*)d_in[15];
    const float* p2_w = (const float*)d_in[16];
    const float* p2_b = (const float*)d_in[17];
    const float* w_bn1_g = (const float*)d_in[18];
    const float* w_bn1_b = (const float*)d_in[19];
    const float* w_bn1_m = (const float*)d_in[20];
    const float* w_bn1_v = (const float*)d_in[21];
    const float* w1_w = (const float*)d_in[22];
    const float* w1_b = (const float*)d_in[23];
    const float* w_bn2_g = (const float*)d_in[24];
    const float* w_bn2_b = (const float*)d_in[25];
    const float* w_bn2_m = (const float*)d_in[26];
    const float* w_bn2_v = (const float*)d_in[27];
    const float* w2_w = (const float*)d_in[28];
    const float* w2_b = (const float*)d_in[29];

    const size_t PTS = (size_t)B_ * N_;        // 40000
    char* wsb = (char*)d_ws;
    unsigned int* kv_t = (unsigned int*)wsb;                    // [PTS][64] u32 (10.24MB)
    unsigned int* xq2  = (unsigned int*)(wsb + PTS * C_ * 4);   // [PTS][32] u32 (5.12MB)
    uint4* wtab  = (uint4*)(wsb + PTS * C_ * 4 + PTS * C_ * 2); // 1536 uint4
    uint4* a1tab = wtab + 1536;                                 // 128 uint4
    uint2* a2tab = (uint2*)(a1tab + 128);                       // 64 uint2
    float* cz    = (float*)(a2tab + 64);                        // 48 f32
    float4* ctab = (float4*)(cz + 48);                          // 64 float4
    float4* ptab = ctab + 64;                                   // 64 float4

    setup_kernel<<<6, 256, 0, stream>>>(
        wq, wk, wv, bq, bk, bv, w1_w, w1_b, w2_w, w2_b,
        w_bn1_g, w_bn1_b, w_bn1_m, w_bn1_v,
        w_bn2_g, w_bn2_b, w_bn2_m, w_bn2_v,
        p2_w, p2_b,
        wtab, a1tab, a2tab, cz, ctab, ptab);

    proj_kernel<<<(B_ * N_) / 16, 256, 0, stream>>>(
        q, k, coord,
        p1_w, p1_b, p_bn_g, p_bn_b, p_bn_m, p_bn_v,
        wtab, ctab, ptab, xq2, kv_t);

    attn_kernel<<<(B_ * N_) / 8, 512, 0, stream>>>(
        nbr, xq2, kv_t, a1tab, a2tab, cz,
        (float*)d_out);
}